// Round 5
// baseline (76518.634 us; speedup 1.0000x reference)
//
#include <hip/hip_runtime.h>
#include <math.h>

// SynchronGRU: 8-layer Keras-v2 GRU (reset_after=True), B=512 T=256 F=8 U=128.
// Persistent-weights design: thread n<384 holds fp32 input-kernel column n,
// thread 384+n holds recurrent-kernel column n (32 named float4 regs each).
// Activations broadcast via LDS. 2 batch rows/block, 256 blocks, 768 threads.
//
// R1-R4 lesson: __launch_bounds__(768,3) and amdgpu_waves_per_eu(3,3) did NOT
// change the RA's budget (VGPR_Count=84 every time = 512/6 for 6 waves/EU);
// all 128 weight regs spilled, reloaded per step -> 164 GB scratch FETCH.
// Fix: occupancy capped PHYSICALLY via LDS: one 100 KB __shared__ block means
// at most 1 block/CU (12 waves, 3/EU), so the RA budget is ~168 VGPRs by
// construction. Real buffers (~8 KB) are carved from the big array.

namespace {

constexpr int kB = 512;
constexpr int kT = 256;
constexpr int kF = 8;
constexpr int kU = 128;
constexpr int kG = 384;   // 3*U, gate order [z, r, h]
constexpr int kL = 8;
constexpr int kRows = 2;  // batch rows per block
constexpr int kThreads = 2 * kG;  // 768 = 12 waves
constexpr int kSmemFloats = 25600;  // 100 KB > 80 KB -> hard 1 block/CU

// X-macro over the 32 float4 weight registers
#define W_FOREACH(X) \
  X(0) X(1) X(2) X(3) X(4) X(5) X(6) X(7) \
  X(8) X(9) X(10) X(11) X(12) X(13) X(14) X(15) \
  X(16) X(17) X(18) X(19) X(20) X(21) X(22) X(23) \
  X(24) X(25) X(26) X(27) X(28) X(29) X(30) X(31)

__global__
__attribute__((amdgpu_flat_work_group_size(kThreads, kThreads),
               amdgpu_waves_per_eu(3, 3)))
void gru_all(
    const float* __restrict__ xin,      // (B,T,F)
    const float* __restrict__ init_h,   // (L,B,U)
    const float* __restrict__ kernel0,  // (F,3U)
    const float* __restrict__ kernels,  // (L-1,U,3U)
    const float* __restrict__ rec_k,    // (L,U,3U)
    const float* __restrict__ biases,   // (L,2,3U)
    float* __restrict__ out)            // (B,T,U) seq out | (L,B,U) states
{
    // One big LDS block: caps occupancy at 1 block/CU (the point of it),
    // real buffers carved from the front (16B-aligned carve offsets).
    __shared__ __align__(16) float smem[kSmemFloats];
    float (*xbuf)[kU] = (float (*)[kU])(smem);              // [kRows][kU]
    float (*hbuf)[kU] = (float (*)[kU])(smem + 256);        // [kRows][kU]
    float (*xacc)[kG] = (float (*)[kG])(smem + 512);        // [kRows][kG]
    float (*hacc)[kG] = (float (*)[kG])(smem + 1280);       // [kRows][kG]

    const int tid  = threadIdx.x;
    const int b0   = blockIdx.x * kRows;
    const bool is_x = tid < kG;             // wave-uniform (384 = 6 waves)
    const int col  = is_x ? tid : tid - kG; // weight column owned

    const int ru_r = (tid >> 7) & 1;  // valid for tid < 256
    const int ru_u = tid & 127;

    float* __restrict__ buf    = out;                        // in-place activations
    float* __restrict__ states = out + (size_t)kB * kT * kU; // final h per layer

    for (int l = 0; l < kL; ++l) {
        // ---- weight column + bias into NAMED registers ----
#define DECLW(i) float4 w##i = {0.f, 0.f, 0.f, 0.f};
        W_FOREACH(DECLW)
#undef DECLW
        float bias_reg;
        if (is_x) {
            bias_reg = biases[l * 2 * kG + col];
            if (l == 0) {
                // only 8 k-values: w0, w1
                w0.x = kernel0[0 * kG + col]; w0.y = kernel0[1 * kG + col];
                w0.z = kernel0[2 * kG + col]; w0.w = kernel0[3 * kG + col];
                w1.x = kernel0[4 * kG + col]; w1.y = kernel0[5 * kG + col];
                w1.z = kernel0[6 * kG + col]; w1.w = kernel0[7 * kG + col];
            } else {
                const float* Wp = kernels + (size_t)(l - 1) * kU * kG + col;
#define LOADW(i) w##i.x = Wp[(size_t)(4*i+0)*kG]; w##i.y = Wp[(size_t)(4*i+1)*kG]; \
                 w##i.z = Wp[(size_t)(4*i+2)*kG]; w##i.w = Wp[(size_t)(4*i+3)*kG];
                W_FOREACH(LOADW)
#undef LOADW
            }
        } else {
            bias_reg = biases[l * 2 * kG + kG + col];
            const float* Wp = rec_k + (size_t)l * kU * kG + col;
#define LOADW(i) w##i.x = Wp[(size_t)(4*i+0)*kG]; w##i.y = Wp[(size_t)(4*i+1)*kG]; \
                 w##i.z = Wp[(size_t)(4*i+2)*kG]; w##i.w = Wp[(size_t)(4*i+3)*kG];
            W_FOREACH(LOADW)
#undef LOADW
        }
        // ---- init h ----
        if (tid < kRows * kU) {
            hbuf[ru_r][ru_u] = init_h[(size_t)l * kB * kU + (size_t)(b0 + ru_r) * kU + ru_u];
        }
        __syncthreads();

        for (int t = 0; t < kT; ++t) {
            // ---- stage x_t into LDS ----
            if (l == 0) {
                if (tid < kRows * kF) {
                    const int r = tid >> 3, k = tid & 7;
                    xbuf[r][k] = xin[((size_t)(b0 + r) * kT + t) * kF + k];
                }
            } else {
                if (tid < kRows * kU) {
                    xbuf[ru_r][ru_u] = buf[((size_t)(b0 + ru_r) * kT + t) * kU + ru_u];
                }
            }
            __syncthreads();

            // ---- dot products: x@Wk (waves 0-5) and h@Wr (waves 6-11) ----
            {
                float a0 = bias_reg, a1 = bias_reg;
                if (is_x && l == 0) {
                    a0 += xbuf[0][0]*w0.x + xbuf[0][1]*w0.y + xbuf[0][2]*w0.z + xbuf[0][3]*w0.w
                        + xbuf[0][4]*w1.x + xbuf[0][5]*w1.y + xbuf[0][6]*w1.z + xbuf[0][7]*w1.w;
                    a1 += xbuf[1][0]*w0.x + xbuf[1][1]*w0.y + xbuf[1][2]*w0.z + xbuf[1][3]*w0.w
                        + xbuf[1][4]*w1.x + xbuf[1][5]*w1.y + xbuf[1][6]*w1.z + xbuf[1][7]*w1.w;
                } else {
                    const float4* v0 = (const float4*)(is_x ? xbuf[0] : hbuf[0]);
                    const float4* v1 = (const float4*)(is_x ? xbuf[1] : hbuf[1]);
                    float p0 = 0.f, p1 = 0.f;  // second accumulation chains (ILP)
#define DOT(i) { const float4 c0 = v0[i]; const float4 c1 = v1[i];          \
                 a0 += c0.x * w##i.x; p0 += c0.y * w##i.y;                  \
                 a0 += c0.z * w##i.z; p0 += c0.w * w##i.w;                  \
                 a1 += c1.x * w##i.x; p1 += c1.y * w##i.y;                  \
                 a1 += c1.z * w##i.z; p1 += c1.w * w##i.w; }
                    W_FOREACH(DOT)
#undef DOT
                    a0 += p0; a1 += p1;
                }
                if (is_x) { xacc[0][col] = a0; xacc[1][col] = a1; }
                else      { hacc[0][col] = a0; hacc[1][col] = a1; }
            }
            __syncthreads();

            // ---- gates + state update (threads 0..255 = (row, unit)) ----
            if (tid < kRows * kU) {
                const int r = ru_r, u = ru_u;
                const float xz = xacc[r][u],          hz = hacc[r][u];
                const float xr = xacc[r][kU + u],     hr = hacc[r][kU + u];
                const float xh = xacc[r][2 * kU + u], hp = hacc[r][2 * kU + u];
                const float z  = 1.f / (1.f + __expf(-(xz + hz)));
                const float rr = 1.f / (1.f + __expf(-(xr + hr)));
                const float hh = tanhf(xh + rr * hp);
                const float h  = z * hbuf[r][u] + (1.f - z) * hh;
                hbuf[r][u] = h;
                buf[((size_t)(b0 + r) * kT + t) * kU + u] = h;  // layer output (in-place)
            }
            __syncthreads();  // hbuf ready for next step's h-dot
        }

        // ---- final state of this layer ----
        if (tid < kRows * kU) {
            states[(size_t)l * kB * kU + (size_t)(b0 + ru_r) * kU + ru_u] = hbuf[ru_r][ru_u];
        }
        __syncthreads();
    }
}

}  // namespace

extern "C" void kernel_launch(void* const* d_in, const int* in_sizes, int n_in,
                              void* d_out, int out_size, void* d_ws, size_t ws_size,
                              hipStream_t stream) {
    const float* xin     = (const float*)d_in[0];
    const float* init_h  = (const float*)d_in[1];
    const float* kernel0 = (const float*)d_in[2];
    const float* kernels = (const float*)d_in[3];
    const float* rec_k   = (const float*)d_in[4];
    const float* biases  = (const float*)d_in[5];
    float* out = (float*)d_out;

    dim3 grid(kB / kRows);   // 256 blocks -> 1 per CU (enforced by 100 KB LDS)
    dim3 block(kThreads);    // 768 threads = 12 waves
    gru_all<<<grid, block, 0, stream>>>(xin, init_h, kernel0, kernels, rec_k, biases, out);
}

// Round 6
// 17289.926 us; speedup vs baseline: 4.4256x; 4.4256x over previous
//
#include <hip/hip_runtime.h>
#include <math.h>

// SynchronGRU: 8-layer Keras-v2 GRU (reset_after=True), B=512 T=256 F=8 U=128.
// STREAMING design: R1-R5 proved this toolchain's RA budget is pinned at 84
// VGPRs (launch_bounds / waves_per_eu(3,3) / 100KB-LDS clamp all inert), so
// 128 register-resident weights always spill to scratch -> 160 GB per-thread
// scratch reloads (12.5 MB/XCD working set, thrashes L2, L3-bound @2.7TB/s,
// 62 ms). Instead: re-read weights from GLOBAL each timestep. All blocks read
// the same 393 KB/layer -> L2-resident per XCD -> served at L1/L2-fill rate.
// Loads are kept inside the t-loop via an asm-laundered pointer (defeats LICM
// hoist -> no long live ranges -> no spill; ~40 live VGPRs fits the budget).
// Mapping unchanged from R5: thread n<384 = input-proj column n, thread 384+n
// = recurrent column n; 2 batch rows/block; gates on threads 0..255.

namespace {

constexpr int kB = 512;
constexpr int kT = 256;
constexpr int kF = 8;
constexpr int kU = 128;
constexpr int kG = 384;   // 3*U, gate order [z, r, h]
constexpr int kL = 8;
constexpr int kRows = 2;  // batch rows per block
constexpr int kThreads = 2 * kG;  // 768 = 12 waves
constexpr int kSmemFloats = 25600;  // 100 KB pad -> deterministic 1 block/CU

__global__ __launch_bounds__(kThreads) void gru_all(
    const float* __restrict__ xin,      // (B,T,F)
    const float* __restrict__ init_h,   // (L,B,U)
    const float* __restrict__ kernel0,  // (F,3U)
    const float* __restrict__ kernels,  // (L-1,U,3U)
    const float* __restrict__ rec_k,    // (L,U,3U)
    const float* __restrict__ biases,   // (L,2,3U)
    float* __restrict__ out)            // (B,T,U) seq out | (L,B,U) states
{
    __shared__ __align__(16) float smem[kSmemFloats];
    float (*xbuf)[kU] = (float (*)[kU])(smem);              // [kRows][kU]
    float (*hbuf)[kU] = (float (*)[kU])(smem + 256);        // [kRows][kU]
    float (*xacc)[kG] = (float (*)[kG])(smem + 512);        // [kRows][kG]
    float (*hacc)[kG] = (float (*)[kG])(smem + 1280);       // [kRows][kG]

    const int tid  = threadIdx.x;
    const int b0   = blockIdx.x * kRows;
    const bool is_x = tid < kG;             // wave-uniform (384 = 6 waves)
    const int col  = is_x ? tid : tid - kG; // weight column owned

    const int ru_r = (tid >> 7) & 1;  // valid for tid < 256
    const int ru_u = tid & 127;

    float* __restrict__ buf    = out;                        // in-place activations
    float* __restrict__ states = out + (size_t)kB * kT * kU; // final h per layer

    for (int l = 0; l < kL; ++l) {
        // ---- per-layer setup: bias + weight-column base pointer ----
        float bias_reg;
        const float* wcol = nullptr;     // streamed per step (l>0 x, all h)
        float4 w0 = {0,0,0,0}, w1 = {0,0,0,0};  // l==0 x-proj only (K=8)
        if (is_x) {
            bias_reg = biases[l * 2 * kG + col];
            if (l == 0) {
                w0.x = kernel0[0 * kG + col]; w0.y = kernel0[1 * kG + col];
                w0.z = kernel0[2 * kG + col]; w0.w = kernel0[3 * kG + col];
                w1.x = kernel0[4 * kG + col]; w1.y = kernel0[5 * kG + col];
                w1.z = kernel0[6 * kG + col]; w1.w = kernel0[7 * kG + col];
            } else {
                wcol = kernels + (size_t)(l - 1) * kU * kG + col;
            }
        } else {
            bias_reg = biases[l * 2 * kG + kG + col];
            wcol = rec_k + (size_t)l * kU * kG + col;
        }
        // ---- init h ----
        if (tid < kRows * kU) {
            hbuf[ru_r][ru_u] = init_h[(size_t)l * kB * kU + (size_t)(b0 + ru_r) * kU + ru_u];
        }
        __syncthreads();

        for (int t = 0; t < kT; ++t) {
            // ---- stage x_t into LDS ----
            if (l == 0) {
                if (tid < kRows * kF) {
                    const int r = tid >> 3, k = tid & 7;
                    xbuf[r][k] = xin[((size_t)(b0 + r) * kT + t) * kF + k];
                }
            } else {
                if (tid < kRows * kU) {
                    xbuf[ru_r][ru_u] = buf[((size_t)(b0 + ru_r) * kT + t) * kU + ru_u];
                }
            }
            __syncthreads();

            // ---- dot products: weights STREAMED from global (L2-resident) ----
            {
                float a0 = bias_reg, a1 = bias_reg;
                if (is_x && l == 0) {
                    a0 += xbuf[0][0]*w0.x + xbuf[0][1]*w0.y + xbuf[0][2]*w0.z + xbuf[0][3]*w0.w
                        + xbuf[0][4]*w1.x + xbuf[0][5]*w1.y + xbuf[0][6]*w1.z + xbuf[0][7]*w1.w;
                    a1 += xbuf[1][0]*w0.x + xbuf[1][1]*w0.y + xbuf[1][2]*w0.z + xbuf[1][3]*w0.w
                        + xbuf[1][4]*w1.x + xbuf[1][5]*w1.y + xbuf[1][6]*w1.z + xbuf[1][7]*w1.w;
                } else {
                    // Launder the pointer so the 128 loads are formally
                    // loop-variant: LICM cannot hoist them out of the t-loop,
                    // so no 128-wide live range exists to spill.
                    const float* wp = wcol;
                    asm volatile("" : "+v"(wp));
                    const float4* v0 = (const float4*)(is_x ? xbuf[0] : hbuf[0]);
                    const float4* v1 = (const float4*)(is_x ? xbuf[1] : hbuf[1]);
                    float p0 = 0.f, p1 = 0.f;  // second accumulation chains (ILP)
#pragma unroll
                    for (int kq = 0; kq < kU / 4; ++kq) {
                        const float q0 = wp[(size_t)(4 * kq + 0) * kG];
                        const float q1 = wp[(size_t)(4 * kq + 1) * kG];
                        const float q2 = wp[(size_t)(4 * kq + 2) * kG];
                        const float q3 = wp[(size_t)(4 * kq + 3) * kG];
                        const float4 c0 = v0[kq];
                        const float4 c1 = v1[kq];
                        a0 += c0.x * q0; p0 += c0.y * q1;
                        a0 += c0.z * q2; p0 += c0.w * q3;
                        a1 += c1.x * q0; p1 += c1.y * q1;
                        a1 += c1.z * q2; p1 += c1.w * q3;
                    }
                    a0 += p0; a1 += p1;
                }
                if (is_x) { xacc[0][col] = a0; xacc[1][col] = a1; }
                else      { hacc[0][col] = a0; hacc[1][col] = a1; }
            }
            __syncthreads();

            // ---- gates + state update (threads 0..255 = (row, unit)) ----
            if (tid < kRows * kU) {
                const int r = ru_r, u = ru_u;
                const float xz = xacc[r][u],          hz = hacc[r][u];
                const float xr = xacc[r][kU + u],     hr = hacc[r][kU + u];
                const float xh = xacc[r][2 * kU + u], hp = hacc[r][2 * kU + u];
                const float z  = 1.f / (1.f + __expf(-(xz + hz)));
                const float rr = 1.f / (1.f + __expf(-(xr + hr)));
                const float hh = tanhf(xh + rr * hp);
                const float h  = z * hbuf[r][u] + (1.f - z) * hh;
                hbuf[r][u] = h;
                buf[((size_t)(b0 + r) * kT + t) * kU + u] = h;  // layer output (in-place)
            }
            __syncthreads();  // hbuf ready for next step's h-dot
        }

        // ---- final state of this layer ----
        if (tid < kRows * kU) {
            states[(size_t)l * kB * kU + (size_t)(b0 + ru_r) * kU + ru_u] = hbuf[ru_r][ru_u];
        }
        __syncthreads();
    }
}

}  // namespace

extern "C" void kernel_launch(void* const* d_in, const int* in_sizes, int n_in,
                              void* d_out, int out_size, void* d_ws, size_t ws_size,
                              hipStream_t stream) {
    const float* xin     = (const float*)d_in[0];
    const float* init_h  = (const float*)d_in[1];
    const float* kernel0 = (const float*)d_in[2];
    const float* kernels = (const float*)d_in[3];
    const float* rec_k   = (const float*)d_in[4];
    const float* biases  = (const float*)d_in[5];
    float* out = (float*)d_out;

    dim3 grid(kB / kRows);   // 256 blocks -> 1 per CU (LDS pad enforces)
    dim3 block(kThreads);    // 768 threads = 12 waves
    gru_all<<<grid, block, 0, stream>>>(xin, init_h, kernel0, kernels, rec_k, biases, out);
}

// Round 7
// 7930.759 us; speedup vs baseline: 9.6483x; 2.1801x over previous
//
#include <hip/hip_runtime.h>
#include <math.h>

// SynchronGRU: 8-layer Keras-v2 GRU (reset_after=True), B=512 T=256 F=8 U=128.
// R6 (17.3 ms) streamed weights as SCALAR dwords (6144 cy/step VMEM-issue) and
// broadcast-read 256 activation floats per thread (9216 cy/step LDS). R7 remap:
// 768 threads = {x,h} side x 4 k-quarters x 96 column-QUADS. Each thread:
// 4 adjacent cols x 2 rows x 32 k -> weight loads are dwordx4 (384 insts/step,
// 1536 cy), LDS reads cut 4x (each h feeds 8 FMA), FMA unchanged (1536 cy).
// Partial sums -> LDS; gate threads (0..255) reduce 4 k-partials + bias.
// Weights re-streamed every step from L2 (asm-laundered pointer defeats LICM;
// R1-R5 proved register-resident weights always spill at this RA budget).

namespace {

constexpr int kB = 512;
constexpr int kT = 256;
constexpr int kF = 8;
constexpr int kU = 128;
constexpr int kG = 384;   // 3*U, gate order [z, r, h]
constexpr int kL = 8;
constexpr int kRows = 2;  // batch rows per block
constexpr int kThreads = 768;       // 12 waves
constexpr int kSmemFloats = 25600;  // 100 KB pad -> deterministic 1 block/CU

// one k-quad of the dot product: 4 weight rows (dwordx4 each) x 2 batch rows
#define DOT_CHUNK(kq)                                                          \
    {                                                                          \
        const float4 h0 = src[(kq)];                                           \
        const float4 h1 = src[32 + (kq)];                                      \
        const float4 wA = *(const float4*)(Wt + (4*(kq)+0)*kG + 4*q);          \
        const float4 wB = *(const float4*)(Wt + (4*(kq)+1)*kG + 4*q);          \
        const float4 wC = *(const float4*)(Wt + (4*(kq)+2)*kG + 4*q);          \
        const float4 wD = *(const float4*)(Wt + (4*(kq)+3)*kG + 4*q);          \
        a0.x += wA.x*h0.x; a0.y += wA.y*h0.x; a0.z += wA.z*h0.x; a0.w += wA.w*h0.x; \
        a1.x += wA.x*h1.x; a1.y += wA.y*h1.x; a1.z += wA.z*h1.x; a1.w += wA.w*h1.x; \
        a0.x += wB.x*h0.y; a0.y += wB.y*h0.y; a0.z += wB.z*h0.y; a0.w += wB.w*h0.y; \
        a1.x += wB.x*h1.y; a1.y += wB.y*h1.y; a1.z += wB.z*h1.y; a1.w += wB.w*h1.y; \
        a0.x += wC.x*h0.z; a0.y += wC.y*h0.z; a0.z += wC.z*h0.z; a0.w += wC.w*h0.z; \
        a1.x += wC.x*h1.z; a1.y += wC.y*h1.z; a1.z += wC.z*h1.z; a1.w += wC.w*h1.z; \
        a0.x += wD.x*h0.w; a0.y += wD.y*h0.w; a0.z += wD.z*h0.w; a0.w += wD.w*h0.w; \
        a1.x += wD.x*h1.w; a1.y += wD.y*h1.w; a1.z += wD.z*h1.w; a1.w += wD.w*h1.w; \
    }

__global__ __launch_bounds__(kThreads) void gru_all(
    const float* __restrict__ xin,      // (B,T,F)
    const float* __restrict__ init_h,   // (L,B,U)
    const float* __restrict__ kernel0,  // (F,3U)
    const float* __restrict__ kernels,  // (L-1,U,3U)
    const float* __restrict__ rec_k,    // (L,U,3U)
    const float* __restrict__ biases,   // (L,2,3U)
    float* __restrict__ out)            // (B,T,U) seq out | (L,B,U) states
{
    __shared__ __align__(16) float smem[kSmemFloats];
    float* xbuf  = smem;          // [2][128]   x_t for both rows
    float* hbuf  = smem + 256;    // [2][128]   h_{t-1} for both rows
    float* pacc  = smem + 512;    // [2 sides][4 kh][2 rows][384] partials
    float* biasx = smem + 6656;   // [384]
    float* biash = smem + 7040;   // [384]

    const int tid  = threadIdx.x;
    const int b0   = blockIdx.x * kRows;
    const bool is_h = (tid >= kG);          // wave-uniform (384 = 6 waves)
    const int s    = is_h ? tid - kG : tid;
    const int kh   = s / 96;                // k-quarter: k in [32*kh, 32*kh+32)
    const int q    = s % 96;                // column quad: cols 4q..4q+3
    const int side = is_h ? 1 : 0;

    const int gr = (tid >> 7) & 1;  // gate-phase row   (valid tid<256)
    const int gu = tid & 127;       // gate-phase unit

    float* __restrict__ buf    = out;                        // in-place activations
    float* __restrict__ states = out + (size_t)kB * kT * kU; // final h per layer

    for (int l = 0; l < kL; ++l) {
        const float* W = is_h ? (rec_k + (size_t)l * kU * kG)
                              : (l == 0 ? kernel0
                                        : kernels + (size_t)(l - 1) * kU * kG);
        // ---- per-layer: biases to LDS, init h ----
        if (tid < kG) biasx[tid]      = biases[l * 2 * kG + tid];
        else          biash[tid - kG] = biases[l * 2 * kG + tid];
        if (tid < kRows * kU)
            hbuf[tid] = init_h[(size_t)l * kB * kU + (size_t)(b0 + gr) * kU + gu];
        __syncthreads();

        for (int t = 0; t < kT; ++t) {
            // ---- phase 1: stage x_t (float4, coalesced) ----
            if (l == 0) {
                if (tid < 4) {
                    const int r = tid >> 1, c = tid & 1;
                    ((float4*)xbuf)[r * 32 + c] =
                        *(const float4*)(xin + ((size_t)(b0 + r) * kT + t) * kF + 4 * c);
                }
            } else {
                if (tid < 64) {
                    const int r = tid >> 5, c = tid & 31;
                    ((float4*)xbuf)[tid] =
                        *(const float4*)(buf + ((size_t)(b0 + r) * kT + t) * kU + 4 * c);
                }
            }
            __syncthreads();

            // ---- phase 2: partial dots (4 cols x 2 rows x 32 k per thread) ----
            {
                const float* Wt = W;
                asm volatile("" : "+v"(Wt));   // loop-variant pointer: no LICM hoist/spill
                const float4* src = (const float4*)(is_h ? hbuf : xbuf);
                float4 a0 = {0.f, 0.f, 0.f, 0.f};
                float4 a1 = {0.f, 0.f, 0.f, 0.f};
                if (l == 0 && !is_h) {
                    if (kh == 0) {           // K=8: only quads kq=0,1
                        DOT_CHUNK(0)
                        DOT_CHUNK(1)
                    }                        // kh>0: zero partials
                } else {
                    const int kqb = kh * 8;  // k-quads [8*kh, 8*kh+8)
#pragma unroll
                    for (int i = 0; i < 8; ++i) DOT_CHUNK(kqb + i)
                }
                float4* p0 = (float4*)(pacc + ((size_t)((side * 4 + kh) * 2 + 0)) * kG + 4 * q);
                float4* p1 = (float4*)(pacc + ((size_t)((side * 4 + kh) * 2 + 1)) * kG + 4 * q);
                *p0 = a0;
                *p1 = a1;
            }
            __syncthreads();

            // ---- phase 3: gates (threads 0..255 = (row, unit)) ----
            if (tid < kRows * kU) {
                float xz = biasx[gu], xr = biasx[kU + gu], xh = biasx[2 * kU + gu];
                float hz = biash[gu], hr = biash[kU + gu], hp = biash[2 * kU + gu];
#pragma unroll
                for (int k2 = 0; k2 < 4; ++k2) {
                    const float* px = pacc + ((size_t)((0 * 4 + k2) * 2 + gr)) * kG;
                    const float* ph = pacc + ((size_t)((1 * 4 + k2) * 2 + gr)) * kG;
                    xz += px[gu]; xr += px[kU + gu]; xh += px[2 * kU + gu];
                    hz += ph[gu]; hr += ph[kU + gu]; hp += ph[2 * kU + gu];
                }
                const float z  = 1.f / (1.f + __expf(-(xz + hz)));
                const float rr = 1.f / (1.f + __expf(-(xr + hr)));
                const float hh = tanhf(xh + rr * hp);
                const float h  = z * hbuf[gr * kU + gu] + (1.f - z) * hh;
                hbuf[gr * kU + gu] = h;
                buf[((size_t)(b0 + gr) * kT + t) * kU + gu] = h;
            }
            __syncthreads();
        }

        // ---- final state of this layer ----
        if (tid < kRows * kU)
            states[(size_t)l * kB * kU + (size_t)(b0 + gr) * kU + gu] = hbuf[tid];
        __syncthreads();
    }
}

}  // namespace

extern "C" void kernel_launch(void* const* d_in, const int* in_sizes, int n_in,
                              void* d_out, int out_size, void* d_ws, size_t ws_size,
                              hipStream_t stream) {
    const float* xin     = (const float*)d_in[0];
    const float* init_h  = (const float*)d_in[1];
    const float* kernel0 = (const float*)d_in[2];
    const float* kernels = (const float*)d_in[3];
    const float* rec_k   = (const float*)d_in[4];
    const float* biases  = (const float*)d_in[5];
    float* out = (float*)d_out;

    dim3 grid(kB / kRows);   // 256 blocks -> 1 per CU (LDS pad enforces)
    dim3 block(kThreads);    // 768 threads = 12 waves
    gru_all<<<grid, block, 0, stream>>>(xin, init_h, kernel0, kernels, rec_k, biases, out);
}